// Round 9
// baseline (355.368 us; speedup 1.0000x reference)
//
#include <hip/hip_runtime.h>
#include <cmath>

#define BB 8
#define CC 256
#define CQ 64
#define NN 4096
#define VROW 4224   // NN + 128 shorts (layout kept from r8; qkv unchanged)
constexpr float INV_N = 1.0f / 4096.0f;   // 2^-12: exact, applied at final store

typedef __attribute__((ext_vector_type(8))) short short8;
typedef __attribute__((ext_vector_type(4))) short short4v;
typedef __attribute__((ext_vector_type(4))) float float4v;

__device__ __forceinline__ short f2bf(float f) {
  union { float f; unsigned u; } x; x.f = f;
  unsigned r = x.u + 0x7fffu + ((x.u >> 16) & 1u);
  return (short)(r >> 16);
}

// ---------------------------------------------------------------------------
// wq/wk fp32 -> bf16 (wv/wg handled by wprep).
// ---------------------------------------------------------------------------
__global__ void wconv_kernel(const float* __restrict__ wq,
                             const float* __restrict__ wk,
                             short* __restrict__ wqb, short* __restrict__ wkb) {
  const int t = blockIdx.x * 256 + threadIdx.x;
  const float* src; short* dst; int idx;
  if (t < 4096) { src = wq; dst = wqb; idx = t; }
  else          { src = wk; dst = wkb; idx = t - 4096; }
  const float4 v = *reinterpret_cast<const float4*>(&src[(size_t)idx * 4]);
  short4v o;
  o[0] = f2bf(v.x); o[1] = f2bf(v.y); o[2] = f2bf(v.z); o[3] = f2bf(v.w);
  *reinterpret_cast<short4v*>(&dst[(size_t)idx * 4]) = o;
}

// ---------------------------------------------------------------------------
// Gamma fold (exact algebra): out = Wg*(V*E)+bg = ((Wg*Wv)X + Wg*bv)*E + bg.
// ---------------------------------------------------------------------------
__global__ void wprep_kernel(const float* __restrict__ wg,
                             const float* __restrict__ wv,
                             const float* __restrict__ bv,
                             short* __restrict__ wvpb, float* __restrict__ bvp) {
  const int o = blockIdx.x, t = threadIdx.x;
  float s = 0.f;
  for (int c = 0; c < 256; ++c)
    s += wg[(size_t)o * 256 + c] * wv[(size_t)c * 256 + t];
  wvpb[(size_t)o * 256 + t] = f2bf(s);

  __shared__ float red[256];
  red[t] = wg[(size_t)o * 256 + t] * bv[t];
  __syncthreads();
  for (int off = 128; off; off >>= 1) {
    if (t < off) red[t] += red[t + off];
    __syncthreads();
  }
  if (t == 0) bvp[o] = red[0];
}

// ---------------------------------------------------------------------------
// Fused q/k/v' conv1x1 — UNCHANGED from round 8 (isolating attn change).
// ---------------------------------------------------------------------------
__global__ __launch_bounds__(256, 2) void qkv_kernel(
    const float* __restrict__ X,
    const short* __restrict__ wqb, const float* __restrict__ bq,
    const short* __restrict__ wkb, const float* __restrict__ bk,
    const short* __restrict__ wvpb, const float* __restrict__ bvp,
    short* __restrict__ qt, short* __restrict__ kt, short* __restrict__ vbf) {
  __shared__ short xt[64 * 264];   // 33792 B; Os buffers alias after frag load
  const int tid = threadIdx.x;
  const int wid = tid >> 6;
  const int lane = tid & 63, quad = lane >> 4, l16 = lane & 15;
  const int b = blockIdx.x, n0 = blockIdx.y * 64;

  float4 xb[16];
#pragma unroll
  for (int p = 0; p < 16; ++p) {
    const int idx = p * 256 + tid;
    const int c = idx >> 4;
    const int n4 = (idx & 15) * 4;
    xb[p] = *reinterpret_cast<const float4*>(
        &X[((size_t)b * CC + c) * NN + n0 + n4]);
  }
#pragma unroll
  for (int p = 0; p < 16; ++p) {
    const int idx = p * 256 + tid;
    const int c = idx >> 4;
    const int n4 = (idx & 15) * 4;
    xt[(n4 + 0) * 264 + c] = f2bf(xb[p].x);
    xt[(n4 + 1) * 264 + c] = f2bf(xb[p].y);
    xt[(n4 + 2) * 264 + c] = f2bf(xb[p].z);
    xt[(n4 + 3) * 264 + c] = f2bf(xb[p].w);
  }
  __syncthreads();

  short8 bfr[8][4];
#pragma unroll
  for (int kk = 0; kk < 8; ++kk)
#pragma unroll
    for (int tm = 0; tm < 4; ++tm)
      bfr[kk][tm] = *reinterpret_cast<const short8*>(
          &xt[(tm * 16 + l16) * 264 + kk * 32 + quad * 8]);
  __syncthreads();   // xt dead; Os aliasing now safe

  short* Os0 = xt;          // [64 o][72 n]
  short* Os1 = xt + 4608;

  for (int ch = 0; ch < 6; ++ch) {
    const short* W; const float* bias; int obase;
    if (ch == 0)      { W = wqb; bias = bq; obase = 0; }
    else if (ch == 1) { W = wkb; bias = bk; obase = 0; }
    else { W = wvpb + (size_t)(ch - 2) * 64 * CC; bias = bvp + (ch - 2) * 64; obase = (ch - 2) * 64; }

    const short* wrow = &W[(size_t)(wid * 16 + l16) * CC + quad * 8];
    short8 wf[8];
#pragma unroll
    for (int kk = 0; kk < 8; ++kk)
      wf[kk] = *reinterpret_cast<const short8*>(wrow + kk * 32);

    float4v acc[4];
#pragma unroll
    for (int tm = 0; tm < 4; ++tm) acc[tm] = float4v{0.f, 0.f, 0.f, 0.f};
#pragma unroll
    for (int kk = 0; kk < 8; ++kk)
#pragma unroll
      for (int tm = 0; tm < 4; ++tm)
        acc[tm] = __builtin_amdgcn_mfma_f32_16x16x32_bf16(wf[kk], bfr[kk][tm], acc[tm], 0, 0, 0);

    if (ch < 2) {
      short* dst = (ch == 0) ? qt : kt;
#pragma unroll
      for (int tm = 0; tm < 4; ++tm) {
        short4v pk;
#pragma unroll
        for (int r = 0; r < 4; ++r)
          pk[r] = f2bf(acc[tm][r] + bias[wid * 16 + quad * 4 + r]);
        *reinterpret_cast<short4v*>(
            &dst[((size_t)b * NN + n0 + tm * 16 + l16) * 64 + wid * 16 + quad * 4]) = pk;
      }
    } else {
      short* Os = (ch & 1) ? Os1 : Os0;
#pragma unroll
      for (int tm = 0; tm < 4; ++tm)
#pragma unroll
        for (int r = 0; r < 4; ++r)
          Os[(wid * 16 + quad * 4 + r) * 72 + tm * 16 + l16] =
              f2bf(acc[tm][r] + bias[wid * 16 + quad * 4 + r]);
      __syncthreads();
      const int o = tid >> 2, ng = (tid & 3) * 16;
      const int orow = obase + o;
      const short8 s0 = *reinterpret_cast<const short8*>(&Os[o * 72 + ng]);
      const short8 s1 = *reinterpret_cast<const short8*>(&Os[o * 72 + ng + 8]);
      short* vp = &vbf[((size_t)b * CC + orow) * VROW + n0 + ng];
      *reinterpret_cast<short8*>(vp) = s0;
      *reinterpret_cast<short8*>(vp + 8) = s1;
    }
  }
}

// ---------------------------------------------------------------------------
// Fused MFMA attention, v10 — BARRIER-FREE / LDS-FREE dataflow:
//  Each wave computes the FULL 64x64 E tile itself (QK duplicated 4x across
//  waves) so E never leaves registers. The QK output-register layout is made
//  to coincide with PV's B-fragment layout by PERMUTING which q rows each
//  A-fragment loads:  nperm(ng,i) = (ng&2)*16 + (i>>2)*8 + (ng&1)*4 + (i&3).
//  Then D[i=quad*4+r][j=l16] = energy[n = quad*8 + (ng&1)*4 + r][m = l16] ==
//  exactly B[k=quad*8+e][j=l16] after elu+f2bf. Zero shuffles, zero LDS,
//  ZERO barriers in the main loop -> no lockstep, waves free-run; the
//  2-phase barrier structure (the invariant ~50% stall, r2-r8) is gone.
//  Per wave/iter: 32 QK + 32 PV MFMA, 16 global loads. Numerics path
//  identical to r8 (same f2bf points).
// grid (B, 64), 256 thr, 2 blocks/CU.
// ---------------------------------------------------------------------------
__global__ __launch_bounds__(256, 2) void attn_kernel(
    const short* __restrict__ qt, const short* __restrict__ kt,
    const short* __restrict__ vbf, const float* __restrict__ bg,
    float* __restrict__ out) {
  const int tid = threadIdx.x;
  const int wid = tid >> 6;
  const int lane = tid & 63, quad = lane >> 4, l16 = lane & 15;
  const int b = blockIdx.x, m0 = blockIdx.y * 64;

  // K B-frags for all 4 m-tiles (j = l16 = m-local)
  short8 bkf[4][2];
#pragma unroll
  for (int tm = 0; tm < 4; ++tm)
#pragma unroll
    for (int ch = 0; ch < 2; ++ch)
      bkf[tm][ch] = *reinterpret_cast<const short8*>(
          &kt[((size_t)b * NN + m0 + tm * 16 + l16) * 64 + ch * 32 + quad * 8]);

  // permuted q-row offsets: A-frag ng, lane-row i=l16 loads q row nperm
  int nperm[4];
#pragma unroll
  for (int ng = 0; ng < 4; ++ng)
    nperm[ng] = (ng & 2) * 16 + (l16 >> 2) * 8 + (ng & 1) * 4 + (l16 & 3);
  const short* qbase = &qt[(size_t)b * NN * 64 + quad * 8];

  // V A-frags: c = wid*64 + tc*16 + l16 (i = l16 = c-local)
  const short* vrow[4];
#pragma unroll
  for (int tc = 0; tc < 4; ++tc)
    vrow[tc] = &vbf[((size_t)b * CC + wid * 64 + tc * 16 + l16) * VROW + quad * 8];

  float4v acc[4][4];
#pragma unroll
  for (int i = 0; i < 4; ++i)
#pragma unroll
    for (int j = 0; j < 4; ++j) acc[i][j] = float4v{0.f, 0.f, 0.f, 0.f};

  for (int it = 0; it < 64; ++it) {
    const int nb = it * 64;

    // q A-frags (permuted rows) and V A-frags for this iter
    short8 aq[4][2];
#pragma unroll
    for (int ng = 0; ng < 4; ++ng) {
      const short* qp = qbase + (size_t)(nb + nperm[ng]) * 64;
      aq[ng][0] = *reinterpret_cast<const short8*>(qp);
      aq[ng][1] = *reinterpret_cast<const short8*>(qp + 32);
    }
    short8 av[4][2];
#pragma unroll
    for (int tc = 0; tc < 4; ++tc) {
      av[tc][0] = *reinterpret_cast<const short8*>(vrow[tc] + nb);
      av[tc][1] = *reinterpret_cast<const short8*>(vrow[tc] + nb + 32);
    }

    // per m-tile: QK (8 MFMA) -> elu -> B-frags -> PV (8 MFMA).
    // tm chains are independent -> compiler interleaves QK(tm+1) with
    // elu/PV(tm); 2 waves/SIMD fill the rest.
#pragma unroll
    for (int tm = 0; tm < 4; ++tm) {
      float4v s[4];
#pragma unroll
      for (int ng = 0; ng < 4; ++ng) {
        float4v t = {0.f, 0.f, 0.f, 0.f};
        t = __builtin_amdgcn_mfma_f32_16x16x32_bf16(aq[ng][0], bkf[tm][0], t, 0, 0, 0);
        t = __builtin_amdgcn_mfma_f32_16x16x32_bf16(aq[ng][1], bkf[tm][1], t, 0, 0, 0);
        s[ng] = t;
      }
      // elu + pack: e0 covers n-local 0..31 (k-half 0), e1 covers 32..63
      short8 e0, e1;
#pragma unroll
      for (int r = 0; r < 4; ++r) {
        float v0 = s[0][r];
        v0 = (v0 > 0.f) ? v0 : (__expf(v0) - 1.f);
        e0[r] = f2bf(v0);
        float v1 = s[1][r];
        v1 = (v1 > 0.f) ? v1 : (__expf(v1) - 1.f);
        e0[4 + r] = f2bf(v1);
        float v2 = s[2][r];
        v2 = (v2 > 0.f) ? v2 : (__expf(v2) - 1.f);
        e1[r] = f2bf(v2);
        float v3 = s[3][r];
        v3 = (v3 > 0.f) ? v3 : (__expf(v3) - 1.f);
        e1[4 + r] = f2bf(v3);
      }
      // PV for this m-tile
#pragma unroll
      for (int tc = 0; tc < 4; ++tc) {
        acc[tc][tm] = __builtin_amdgcn_mfma_f32_16x16x32_bf16(av[tc][0], e0, acc[tc][tm], 0, 0, 0);
        acc[tc][tm] = __builtin_amdgcn_mfma_f32_16x16x32_bf16(av[tc][1], e1, acc[tc][tm], 0, 0, 0);
      }
    }
  }

  // ---- direct store: out = acc*INV_N + bg (gamma pre-folded into V) ----
#pragma unroll
  for (int tc = 0; tc < 4; ++tc) {
#pragma unroll
    for (int r = 0; r < 4; ++r) {
      const int o = wid * 64 + tc * 16 + quad * 4 + r;
      const float bgv = bg[o];
#pragma unroll
      for (int tm = 0; tm < 4; ++tm) {
        out[((size_t)b * CC + o) * NN + m0 + tm * 16 + l16] =
            acc[tc][tm][r] * INV_N + bgv;
      }
    }
  }
}

// ---------------------------------------------------------------------------
extern "C" void kernel_launch(void* const* d_in, const int* in_sizes, int n_in,
                              void* d_out, int out_size, void* d_ws,
                              size_t ws_size, hipStream_t stream) {
  const float* x  = (const float*)d_in[0];
  const float* wq = (const float*)d_in[1];
  const float* bq = (const float*)d_in[2];
  const float* wk = (const float*)d_in[3];
  const float* bk = (const float*)d_in[4];
  const float* wv = (const float*)d_in[5];
  const float* bv = (const float*)d_in[6];
  const float* wg = (const float*)d_in[7];
  const float* bg = (const float*)d_in[8];
  float* out = (float*)d_out;

  short* qt   = (short*)d_ws;                        // [B][N][64] bf16, 4 MB
  short* kt   = qt + (size_t)BB * NN * CQ;           // 4 MB
  short* vbf  = kt + (size_t)BB * NN * CQ;           // [B][C][VROW], 16.5 MiB
  short* wqb  = vbf + (size_t)BB * CC * VROW;
  short* wkb  = wqb + (size_t)CQ * CC;
  short* wvpb = wkb + (size_t)CQ * CC;               // folded Wg*Wv, 128 KB
  float* bvp  = (float*)(wvpb + (size_t)CC * CC);    // folded Wg*bv, 1 KB

  wconv_kernel<<<dim3(32), 256, 0, stream>>>(wq, wk, wqb, wkb);
  wprep_kernel<<<dim3(256), 256, 0, stream>>>(wg, wv, bv, wvpb, bvp);
  qkv_kernel<<<dim3(BB, NN / 64), 256, 0, stream>>>(x, wqb, bq, wkb, bk,
                                                    wvpb, bvp, qt, kt, vbf);
  attn_kernel<<<dim3(BB, NN / 64), 256, 0, stream>>>(qt, kt, vbf, bg, out);
}